// Round 13
// baseline (21.491 us; speedup 1.0000x reference)
//
#include <hip/hip_runtime.h>

// 8192 rows x 64 cols complex, separate re/im planes; out = [2][8192][64] f32.
// Row r = h*64 + m. Gate angle[i] acts on row-bit (12-i): m-bit j <-> angle[12-j],
// h-bit j <-> angle[6-j]. Gates commute.
// SINGLE kernel, XCD-LOCAL two-phase: XCD x owns columns 8x..8x+7 (4 col-pairs).
// Blocks read their die via s_getreg(HW_REG_XCC_ID) and claim work items for
// their own colset from per-XCD atomic queues -> A-writer, barrier, B-reader of
// any ws byte share one XCD's L2. ws stores/loads use sc0 (L1 bypass, L2 hit);
// no sc1, no cache-maintenance fences, no cross-XCD ws traffic.
// Phase A item j (32/XCD): h in {4j..4j+3}, all m, 4 cp. radix-4: m-bits {0,1}
//   in regs at load, {2,3} LDS RT, {4,5} in regs at ws store.
// Phase B item j (32/XCD): m in {2j,2j+1}, all h, 4 cp. h-bits {5,6} in regs at
//   ws load, {3,4} and {1,2} LDS RTs, {0} in regs at out store.
// ws region x: [(m*4+cq)*128 + h] f4 (512 KB) -> B loads contiguous, A scatters.
#define PLANE (8192 * 64)

typedef float f4 __attribute__((ext_vector_type(4)));
typedef float f2 __attribute__((ext_vector_type(2)));

__device__ __forceinline__ void gate_coeffs(float theta, float& a, float& s) {
    // truncated series, CUTOFF=10: a ~ cos(theta/2) thru t^10, s ~ sin(theta/2) thru t^9
    float t = 0.5f * theta;
    float u = t * t;
    s = t * (1.f + u * (-1.f/6.f + u * (1.f/120.f + u * (-1.f/5040.f + u * (1.f/362880.f)))));
    a = 1.f + u * (-0.5f + u * (1.f/24.f + u * (-1.f/720.f + u * (1.f/40320.f + u * (-1.f/3628800.f)))));
}

// v = (reA, imA, reB, imB) for two cols of one row; RX pair update.
__device__ __forceinline__ void bf(f4& v0, f4& v1, float a, float s) {
    f4 n0, n1;
    n0.x = a * v0.x + s * v1.y;  n0.y = a * v0.y - s * v1.x;
    n0.z = a * v0.z + s * v1.w;  n0.w = a * v0.w - s * v1.z;
    n1.x = a * v1.x + s * v0.y;  n1.y = a * v1.y - s * v0.x;
    n1.z = a * v1.z + s * v0.w;  n1.w = a * v1.w - s * v0.z;
    v0 = n0; v1 = n1;
}

// Phase-B LDS slot map [128 h][8 c], XOR swizzle: verified 8 lanes/bank-quad for
// trip1 writes (hL-major), trips 2/3 strided RTs; trip4 reads <=2-way (free).
__device__ __forceinline__ int slotB(int h, int c) { return h * 8 + (c ^ (h & 7)); }

__global__ __launch_bounds__(256) void rx_xcd(const float* __restrict__ xr,
                                              const float* __restrict__ xi,
                                              const float* __restrict__ angle,
                                              f4* __restrict__ ws4,
                                              unsigned int* __restrict__ cnt,
                                              float* __restrict__ out) {
    __shared__ f4 l4[1024];            // 16 KB, reused by both phases
    __shared__ int sh_idx;
    const int t = threadIdx.x;

    unsigned int xid;
    asm volatile("s_getreg_b32 %0, hwreg(HW_REG_XCC_ID)" : "=s"(xid));
    const int x = (int)(xid & 7u);     // this block's die = its colset

    f4* wsx = ws4 + (size_t)x * 32768;             // 512 KB region, L2(x)-resident
    unsigned int* aq = cnt + x * 16;               // A-claim queue
    unsigned int* ad = cnt + 128 + x * 16;         // A-done count
    unsigned int* bq = cnt + 256 + x * 16;         // B-claim queue

    const f2* xr2 = (const f2*)xr;
    const f2* xi2 = (const f2*)xi;

    // ================= Phase A: claim items until queue empty =================
    for (;;) {
        __syncthreads();               // protect sh_idx + l4 reuse
        if (t == 0)
            sh_idx = (int)__hip_atomic_fetch_add(aq, 1u, __ATOMIC_RELAXED,
                                                 __HIP_MEMORY_SCOPE_AGENT);
        __syncthreads();
        const int j = sh_idx;
        if (j >= 32) break;

        const int col = t & 15, rq = t >> 4;       // col = grp*4+cq, rq 0..15
        const int grp = col >> 2, cq = col & 3;
        const int h = 4 * j + grp;

        // trip 1: global -> regs (nontemporal), m-bits 0,1, write LDS [m][col]
        {
            float a0, s0, a1, s1;
            gate_coeffs(angle[12], a0, s0);        // m-bit 0
            gate_coeffs(angle[11], a1, s1);        // m-bit 1
            int gb = (h * 64 + 4 * rq) * 32 + x * 4 + cq;   // f2 idx, m = 4rq
            f2 re, im; f4 v0, v1, v2, v3;
            re = __builtin_nontemporal_load(xr2 + gb);
            im = __builtin_nontemporal_load(xi2 + gb);      v0 = (f4){re.x, im.x, re.y, im.y};
            re = __builtin_nontemporal_load(xr2 + gb + 32);
            im = __builtin_nontemporal_load(xi2 + gb + 32); v1 = (f4){re.x, im.x, re.y, im.y};
            re = __builtin_nontemporal_load(xr2 + gb + 64);
            im = __builtin_nontemporal_load(xi2 + gb + 64); v2 = (f4){re.x, im.x, re.y, im.y};
            re = __builtin_nontemporal_load(xr2 + gb + 96);
            im = __builtin_nontemporal_load(xi2 + gb + 96); v3 = (f4){re.x, im.x, re.y, im.y};
            bf(v0, v1, a0, s0); bf(v2, v3, a0, s0);
            bf(v0, v2, a1, s1); bf(v1, v3, a1, s1);
            l4[(4 * rq + 0) * 16 + col] = v0;
            l4[(4 * rq + 1) * 16 + col] = v1;
            l4[(4 * rq + 2) * 16 + col] = v2;
            l4[(4 * rq + 3) * 16 + col] = v3;
        }
        __syncthreads();

        // trip 2: LDS round-trip, m-bits 2,3 (rows base+{0,4,8,12})
        {
            float a2, s2, a3, s3;
            gate_coeffs(angle[10], a2, s2);        // m-bit 2
            gate_coeffs(angle[9],  a3, s3);        // m-bit 3
            int base = ((rq >> 2) << 4) | (rq & 3);
            f4 w0 = l4[(base     ) * 16 + col], w1 = l4[(base +  4) * 16 + col];
            f4 w2 = l4[(base +  8) * 16 + col], w3 = l4[(base + 12) * 16 + col];
            bf(w0, w1, a2, s2); bf(w2, w3, a2, s2);
            bf(w0, w2, a3, s3); bf(w1, w3, a3, s3);
            l4[(base     ) * 16 + col] = w0; l4[(base +  4) * 16 + col] = w1;
            l4[(base +  8) * 16 + col] = w2; l4[(base + 12) * 16 + col] = w3;
        }
        __syncthreads();

        // trip 3: LDS read, m-bits 4,5 (rows rq+{0,16,32,48}), sc0 store to ws
        {
            float a4, s4, a5, s5;
            gate_coeffs(angle[8], a4, s4);         // m-bit 4
            gate_coeffs(angle[7], a5, s5);         // m-bit 5
            f4 w0 = l4[(rq     ) * 16 + col], w1 = l4[(rq + 16) * 16 + col];
            f4 w2 = l4[(rq + 32) * 16 + col], w3 = l4[(rq + 48) * 16 + col];
            bf(w0, w1, a4, s4); bf(w2, w3, a4, s4);
            bf(w0, w2, a5, s5); bf(w1, w3, a5, s5);
            const f4* p0 = wsx + ((size_t)((rq     ) * 4 + cq) * 128 + h);
            const f4* p1 = wsx + ((size_t)((rq + 16) * 4 + cq) * 128 + h);
            const f4* p2 = wsx + ((size_t)((rq + 32) * 4 + cq) * 128 + h);
            const f4* p3 = wsx + ((size_t)((rq + 48) * 4 + cq) * 128 + h);
            asm volatile("global_store_dwordx4 %0, %4, off sc0\n\t"
                         "global_store_dwordx4 %1, %5, off sc0\n\t"
                         "global_store_dwordx4 %2, %6, off sc0\n\t"
                         "global_store_dwordx4 %3, %7, off sc0"
                         :: "v"(p0), "v"(p1), "v"(p2), "v"(p3),
                            "v"(w0), "v"(w1), "v"(w2), "v"(w3) : "memory");
        }
        asm volatile("s_waitcnt vmcnt(0)" ::: "memory");   // stores in L2(x)
        __syncthreads();
        if (t == 0)
            __hip_atomic_fetch_add(ad, 1u, __ATOMIC_RELAXED, __HIP_MEMORY_SCOPE_AGENT);
    }

    // ============ per-XCD barrier: wait for all 32 A-items (bounded) ==========
    if (t == 0) {
        int guard = 0;
        while (__hip_atomic_load(ad, __ATOMIC_RELAXED, __HIP_MEMORY_SCOPE_AGENT) < 32u
               && ++guard < 2000000)
            __builtin_amdgcn_s_sleep(8);
    }
    __syncthreads();

    // ================= Phase B: claim items until queue empty =================
    for (;;) {
        __syncthreads();
        if (t == 0)
            sh_idx = (int)__hip_atomic_fetch_add(bq, 1u, __ATOMIC_RELAXED,
                                                 __HIP_MEMORY_SCOPE_AGENT);
        __syncthreads();
        const int j = sh_idx;
        if (j >= 32) break;                        // m-pair {2j, 2j+1}

        // trip 1: sc0 coalesced loads (512B runs), h-bits 5,6, write LDS swz
        {
            float a5, s5, a6, s6;
            gate_coeffs(angle[1], a5, s5);         // h-bit 5
            gate_coeffs(angle[0], a6, s6);         // h-bit 6
            const int hL = t & 31, cB = t >> 5;    // cB = mo*4+cq (0..7)
            const f4* src = wsx + (size_t)j * 1024 + cB * 128 + hL;
            f4 v0, v1, v2, v3;
            asm volatile("global_load_dwordx4 %0, %4, off sc0\n\t"
                         "global_load_dwordx4 %1, %5, off sc0\n\t"
                         "global_load_dwordx4 %2, %6, off sc0\n\t"
                         "global_load_dwordx4 %3, %7, off sc0\n\t"
                         "s_waitcnt vmcnt(0)"
                         : "=&v"(v0), "=&v"(v1), "=&v"(v2), "=&v"(v3)
                         : "v"(src), "v"(src + 32), "v"(src + 64), "v"(src + 96)
                         : "memory");
            bf(v0, v1, a5, s5); bf(v2, v3, a5, s5);
            bf(v0, v2, a6, s6); bf(v1, v3, a6, s6);
            l4[slotB(hL,      cB)] = v0;
            l4[slotB(hL + 32, cB)] = v1;
            l4[slotB(hL + 64, cB)] = v2;
            l4[slotB(hL + 96, cB)] = v3;
        }
        __syncthreads();

        // trip 2: LDS round-trip, h-bits 3,4 (h = base+{0,8,16,24})
        {
            float a3, s3, a4, s4;
            gate_coeffs(angle[3], a3, s3);         // h-bit 3
            gate_coeffs(angle[2], a4, s4);         // h-bit 4
            const int cB = t & 7, hq = t >> 3;
            int base = ((hq >> 3) << 5) | (hq & 7);
            f4 w0 = l4[slotB(base,      cB)], w1 = l4[slotB(base +  8, cB)];
            f4 w2 = l4[slotB(base + 16, cB)], w3 = l4[slotB(base + 24, cB)];
            bf(w0, w1, a3, s3); bf(w2, w3, a3, s3);
            bf(w0, w2, a4, s4); bf(w1, w3, a4, s4);
            l4[slotB(base,      cB)] = w0; l4[slotB(base +  8, cB)] = w1;
            l4[slotB(base + 16, cB)] = w2; l4[slotB(base + 24, cB)] = w3;
        }
        __syncthreads();

        // trip 3: LDS round-trip, h-bits 1,2 (h = b+{0,2,4,6})
        {
            float a1, s1, a2, s2;
            gate_coeffs(angle[5], a1, s1);         // h-bit 1
            gate_coeffs(angle[4], a2, s2);         // h-bit 2
            const int cB = t & 7, hq = t >> 3;
            int b = ((hq >> 1) << 3) | (hq & 1);
            f4 w0 = l4[slotB(b,     cB)], w1 = l4[slotB(b + 2, cB)];
            f4 w2 = l4[slotB(b + 4, cB)], w3 = l4[slotB(b + 6, cB)];
            bf(w0, w1, a1, s1); bf(w2, w3, a1, s1);
            bf(w0, w2, a2, s2); bf(w1, w3, a2, s2);
            l4[slotB(b,     cB)] = w0; l4[slotB(b + 2, cB)] = w1;
            l4[slotB(b + 4, cB)] = w2; l4[slotB(b + 6, cB)] = w3;
        }
        __syncthreads();

        // trip 4: h-bit 0 in regs, de-interleave, nontemporal 16B stores
        {
            float a0, s0;
            gate_coeffs(angle[6], a0, s0);         // h-bit 0
            const int hd = t >> 2, u = t & 3;      // hd 0..63 = h-pair
            const int mo = u >> 1, cqh = u & 1;
            const int c0 = mo * 4 + 2 * cqh, c1 = c0 + 1;
            f4 u0 = l4[slotB(2 * hd,     c0)], u1 = l4[slotB(2 * hd,     c1)];
            f4 v0 = l4[slotB(2 * hd + 1, c0)], v1 = l4[slotB(2 * hd + 1, c1)];
            bf(u0, v0, a0, s0);
            bf(u1, v1, a0, s0);
            f4* outre4 = (f4*)out;
            f4* outim4 = (f4*)(out + PLANE);
            const int m = 2 * j + mo;
            // row r0 = (2hd)*64 + m; r1 = r0 + 64 -> +64*16 = +1024 f4
            int o = ((2 * hd) * 64 + m) * 16 + x * 2 + cqh;
            __builtin_nontemporal_store((f4){u0.x, u0.z, u1.x, u1.z}, outre4 + o);
            __builtin_nontemporal_store((f4){u0.y, u0.w, u1.y, u1.w}, outim4 + o);
            __builtin_nontemporal_store((f4){v0.x, v0.z, v1.x, v1.z}, outre4 + o + 1024);
            __builtin_nontemporal_store((f4){v0.y, v0.w, v1.y, v1.w}, outim4 + o + 1024);
        }
    }
}

extern "C" void kernel_launch(void* const* d_in, const int* in_sizes, int n_in,
                              void* d_out, int out_size, void* d_ws, size_t ws_size,
                              hipStream_t stream) {
    const float* xr    = (const float*)d_in[0];
    const float* xi    = (const float*)d_in[1];
    const float* angle = (const float*)d_in[2];
    float* out = (float*)d_out;
    f4*    ws4 = (f4*)d_ws;                                        // 8 x 512 KB regions
    unsigned int* cnt = (unsigned int*)((char*)d_ws + (4u << 20)); // 3x8 strided counters

    hipMemsetAsync(cnt, 0, 1536, stream);                          // reset each replay
    rx_xcd<<<256, 256, 0, stream>>>(xr, xi, angle, ws4, cnt, out);
}

// Round 14
// 13.993 us; speedup vs baseline: 1.5358x; 1.5358x over previous
//
#include <hip/hip_runtime.h>

// 8192 rows x 64 cols complex, separate re/im float planes; out = [2][8192][64].
// Row r = h*64 + m (h = r>>6, m = r&63). Gate angle[i] acts on row-bit (12-i);
// m-bit j <-> angle[12-j], h-bit j <-> angle[6-j]. Gates commute (distinct bits).
// Kernel A: m-bits. radix-4: bits {0,1} fused into global load (registers),
//   {2,3} one LDS round-trip, {4,5} fused into ws store. 2 barriers.
// Kernel B: h-bits. {5,6} fused into ws load, {3,4} and {1,2} LDS round-trips,
//   {0} fused into out store. 3 barriers.
// f4 = (re,im) x 2 adjacent cols. cp32 = col-pair 0..31; q = cp32>>3, cb = cp32&7.
// ws[(m*4+q)*1024 + h*8 + cb] = B's linear LDS order -> B loads 1KB/wave contiguous.
// LDS layouts keep the col-pair in the low slot bits -> every strided access is
// exactly 8 lanes/bank-quad (the b128 floor); no swizzle required.
//
// Session conclusion: two launches ~10us dominate; all six single-launch fusion
// variants (threadfence, sc0sc1 device-coherent, XCD-local sc0) measured slower
// (156/140/25.3/20.1/21.5 us) than this two-kernel structure.
#define PLANE (8192 * 64)

typedef float f4 __attribute__((ext_vector_type(4)));

__device__ __forceinline__ void gate_coeffs(float theta, float& a, float& s) {
    // truncated series, CUTOFF=10: a ~ cos(theta/2) thru t^10, s ~ sin(theta/2) thru t^9
    float t = 0.5f * theta;
    float u = t * t;
    s = t * (1.f + u * (-1.f/6.f + u * (1.f/120.f + u * (-1.f/5040.f + u * (1.f/362880.f)))));
    a = 1.f + u * (-0.5f + u * (1.f/24.f + u * (-1.f/720.f + u * (1.f/40320.f + u * (-1.f/3628800.f)))));
}

// v = (reA, imA, reB, imB) for two cols of one row; RX pair update.
__device__ __forceinline__ void bf(f4& v0, f4& v1, float a, float s) {
    f4 n0, n1;
    n0.x = a * v0.x + s * v1.y;  n0.y = a * v0.y - s * v1.x;
    n0.z = a * v0.z + s * v1.w;  n0.w = a * v0.w - s * v1.z;
    n1.x = a * v1.x + s * v0.y;  n1.y = a * v1.y - s * v0.x;
    n1.z = a * v1.z + s * v0.w;  n1.w = a * v1.w - s * v0.z;
    v0 = n0; v1 = n1;
}

// Kernel A: m-bits 0..5. Block = rows g*64..+63 x 32 cols (16 col-pairs).
// grid = 128 g x 2 halves = 256 blocks x 256 threads. LDS [64 rows][16 cp] f4.
__global__ __launch_bounds__(256) void rx_low(const float* __restrict__ xr,
                                              const float* __restrict__ xi,
                                              const float* __restrict__ angle,
                                              f4* __restrict__ ws4) {
    __shared__ f4 l4[64 * 16];        // 16 KB
    const int t = threadIdx.x, bid = blockIdx.x;
    const int g = bid >> 1, half = bid & 1;
    const int cp = t & 15, rq = t >> 4;    // cp 0..15, row-quad 0..15

    const float2* xr2 = (const float2*)xr;
    const float2* xi2 = (const float2*)xi;

    // trip 1: global -> regs, bits 0,1 in registers, write LDS
    {
        float a0, s0, a1, s1;
        gate_coeffs(angle[12], a0, s0);            // m-bit 0
        gate_coeffs(angle[11], a1, s1);            // m-bit 1
        f4 v[4];
        #pragma unroll
        for (int k = 0; k < 4; ++k) {              // rows 4rq+k (bits 0,1 free)
            int gi = (g * 64 + 4 * rq + k) * 32 + half * 16 + cp;
            float2 re = xr2[gi], im = xi2[gi];
            v[k] = (f4){re.x, im.x, re.y, im.y};
        }
        bf(v[0], v[1], a0, s0); bf(v[2], v[3], a0, s0);
        bf(v[0], v[2], a1, s1); bf(v[1], v[3], a1, s1);
        #pragma unroll
        for (int k = 0; k < 4; ++k) l4[(4 * rq + k) * 16 + cp] = v[k];
    }
    __syncthreads();

    // trip 2: LDS round-trip, bits 2,3 (rows base+{0,4,8,12}; base bits 2,3 = 0)
    {
        float a2, s2, a3, s3;
        gate_coeffs(angle[10], a2, s2);            // m-bit 2
        gate_coeffs(angle[9],  a3, s3);            // m-bit 3
        int base = ((rq >> 2) << 4) | (rq & 3);
        f4 w0 = l4[(base     ) * 16 + cp], w1 = l4[(base +  4) * 16 + cp];
        f4 w2 = l4[(base +  8) * 16 + cp], w3 = l4[(base + 12) * 16 + cp];
        bf(w0, w1, a2, s2); bf(w2, w3, a2, s2);
        bf(w0, w2, a3, s3); bf(w1, w3, a3, s3);
        l4[(base     ) * 16 + cp] = w0; l4[(base +  4) * 16 + cp] = w1;
        l4[(base +  8) * 16 + cp] = w2; l4[(base + 12) * 16 + cp] = w3;
    }
    __syncthreads();

    // trip 3: LDS read, bits 4,5 in registers (rows rq+{0,16,32,48}), store ws
    {
        float a4, s4, a5, s5;
        gate_coeffs(angle[8], a4, s4);             // m-bit 4
        gate_coeffs(angle[7], a5, s5);             // m-bit 5
        f4 w0 = l4[(rq     ) * 16 + cp], w1 = l4[(rq + 16) * 16 + cp];
        f4 w2 = l4[(rq + 32) * 16 + cp], w3 = l4[(rq + 48) * 16 + cp];
        bf(w0, w1, a4, s4); bf(w2, w3, a4, s4);
        bf(w0, w2, a5, s5); bf(w1, w3, a5, s5);
        const int cp32 = half * 16 + cp, q = cp32 >> 3, cb = cp32 & 7;
        const int e = g * 8 + cb;
        ws4[(size_t)((rq     ) * 4 + q) * 1024 + e] = w0;   // m = rq
        ws4[(size_t)((rq + 16) * 4 + q) * 1024 + e] = w1;   // m = rq+16
        ws4[(size_t)((rq + 32) * 4 + q) * 1024 + e] = w2;   // m = rq+32
        ws4[(size_t)((rq + 48) * 4 + q) * 1024 + e] = w3;   // m = rq+48
    }
}

// Kernel B: h-bits 0..6. Block = m fixed x 16 cols (8 cp), h 0..127.
// grid = 64 m x 4 q = 256 blocks x 256 threads. LDS [128 h][8 cp] f4.
__global__ __launch_bounds__(256) void rx_high(const float* __restrict__ angle,
                                               const f4* __restrict__ ws4,
                                               float* __restrict__ out) {
    __shared__ f4 l4[128 * 8];        // 16 KB
    const int t = threadIdx.x, bid = blockIdx.x;
    const int m = bid >> 2, q = bid & 3;
    const int cp = t & 7, hq = t >> 3;     // cp 0..7, hq 0..31

    // trip 1: ws -> regs (1KB/wave contiguous), h-bits 5,6 in registers, write LDS
    {
        float a5, s5, a6, s6;
        gate_coeffs(angle[1], a5, s5);             // h-bit 5
        gate_coeffs(angle[0], a6, s6);             // h-bit 6
        const f4* src = ws4 + (size_t)(m * 4 + q) * 1024;
        f4 v0 = src[(hq     ) * 8 + cp], v1 = src[(hq + 32) * 8 + cp];
        f4 v2 = src[(hq + 64) * 8 + cp], v3 = src[(hq + 96) * 8 + cp];
        bf(v0, v1, a5, s5); bf(v2, v3, a5, s5);
        bf(v0, v2, a6, s6); bf(v1, v3, a6, s6);
        l4[(hq     ) * 8 + cp] = v0; l4[(hq + 32) * 8 + cp] = v1;
        l4[(hq + 64) * 8 + cp] = v2; l4[(hq + 96) * 8 + cp] = v3;
    }
    __syncthreads();

    // trip 2: LDS round-trip, h-bits 3,4 (h = base+{0,8,16,24}; base bits 3,4 = 0)
    {
        float a3, s3, a4, s4;
        gate_coeffs(angle[3], a3, s3);             // h-bit 3
        gate_coeffs(angle[2], a4, s4);             // h-bit 4
        int base = ((hq >> 3) << 5) | (hq & 7);
        f4 w0 = l4[(base     ) * 8 + cp], w1 = l4[(base +  8) * 8 + cp];
        f4 w2 = l4[(base + 16) * 8 + cp], w3 = l4[(base + 24) * 8 + cp];
        bf(w0, w1, a3, s3); bf(w2, w3, a3, s3);
        bf(w0, w2, a4, s4); bf(w1, w3, a4, s4);
        l4[(base     ) * 8 + cp] = w0; l4[(base +  8) * 8 + cp] = w1;
        l4[(base + 16) * 8 + cp] = w2; l4[(base + 24) * 8 + cp] = w3;
    }
    __syncthreads();

    // trip 3: LDS round-trip, h-bits 1,2 (h = b+{0,2,4,6}; b bits 1,2 = 0)
    {
        float a1, s1, a2, s2;
        gate_coeffs(angle[5], a1, s1);             // h-bit 1
        gate_coeffs(angle[4], a2, s2);             // h-bit 2
        int b = ((hq >> 1) << 3) | (hq & 1);
        f4 w0 = l4[(b    ) * 8 + cp], w1 = l4[(b + 2) * 8 + cp];
        f4 w2 = l4[(b + 4) * 8 + cp], w3 = l4[(b + 6) * 8 + cp];
        bf(w0, w1, a1, s1); bf(w2, w3, a1, s1);
        bf(w0, w2, a2, s2); bf(w1, w3, a2, s2);
        l4[(b    ) * 8 + cp] = w0; l4[(b + 2) * 8 + cp] = w1;
        l4[(b + 4) * 8 + cp] = w2; l4[(b + 6) * 8 + cp] = w3;
    }
    __syncthreads();

    // trip 4: LDS read, h-bit 0 in registers (pairs (2hp, 2hp+1)), store out
    {
        float a0, s0;
        gate_coeffs(angle[6], a0, s0);             // h-bit 0
        float2* outre2 = (float2*)out;
        float2* outim2 = (float2*)(out + PLANE);
        #pragma unroll
        for (int pp = 0; pp < 2; ++pp) {
            int hp = hq + 32 * pp;                 // 0..63
            f4 w0 = l4[(2 * hp) * 8 + cp], w1 = l4[(2 * hp + 1) * 8 + cp];
            bf(w0, w1, a0, s0);
            int o = ((2 * hp) * 64 + m) * 32 + q * 8 + cp;   // row 2hp*64+m
            outre2[o] = make_float2(w0.x, w0.z);
            outim2[o] = make_float2(w0.y, w0.w);
            outre2[o + 2048] = make_float2(w1.x, w1.z);      // row +64
            outim2[o + 2048] = make_float2(w1.y, w1.w);
        }
    }
}

extern "C" void kernel_launch(void* const* d_in, const int* in_sizes, int n_in,
                              void* d_out, int out_size, void* d_ws, size_t ws_size,
                              hipStream_t stream) {
    const float* xr    = (const float*)d_in[0];
    const float* xi    = (const float*)d_in[1];
    const float* angle = (const float*)d_in[2];
    float* out = (float*)d_out;
    f4*    ws4 = (f4*)d_ws;            // 4 MB intermediate

    rx_low <<<256, 256, 0, stream>>>(xr, xi, angle, ws4);
    rx_high<<<256, 256, 0, stream>>>(angle, ws4, out);
}